// Round 8
// baseline (344.049 us; speedup 1.0000x reference)
//
#include <hip/hip_runtime.h>
#include <stdint.h>

#define NN 50000
#define NE 800000
#define CH 512

__device__ __forceinline__ unsigned short f2bf(float f) {
    union { float f; unsigned u; } v; v.f = f;
    unsigned u = v.u;
    unsigned r = u + 0x7FFFu + ((u >> 16) & 1u);
    return (unsigned short)(r >> 16);
}

__device__ __forceinline__ float u2f(unsigned u) {
    union { unsigned u; float f; } v; v.u = u;
    return v.f;
}

typedef short bf16x8 __attribute__((ext_vector_type(8)));
typedef float f32x4 __attribute__((ext_vector_type(4)));
typedef float f32x4e __attribute__((ext_vector_type(4)));
typedef unsigned u32x4e __attribute__((ext_vector_type(4)));

// ---------------- prologue: xb = bf16(x); W1T' transform; cnt = 0 ----------------
__global__ __launch_bounds__(256) void prologue(const f32x4e* __restrict__ x,
                                                u32x4e* __restrict__ xb,
                                                const float* __restrict__ W1,
                                                unsigned short* __restrict__ W1T,
                                                int* __restrict__ cnt) {
    int gid = blockIdx.x * 256 + threadIdx.x;   // 0 .. 3,199,999
    {
        f32x4e a = __builtin_nontemporal_load(&x[2 * gid]);
        f32x4e b = __builtin_nontemporal_load(&x[2 * gid + 1]);
        u32x4e o;
        o.x = (unsigned)f2bf(a.x) | ((unsigned)f2bf(a.y) << 16);
        o.y = (unsigned)f2bf(a.z) | ((unsigned)f2bf(a.w) << 16);
        o.z = (unsigned)f2bf(b.x) | ((unsigned)f2bf(b.y) << 16);
        o.w = (unsigned)f2bf(b.z) | ((unsigned)f2bf(b.w) << 16);
        xb[gid] = o;
    }
    if (gid < CH * CH) {
        const float BETA = 0.40546510810816438f;
        const float OMB  = (float)(1.0 - 0.40546510810816438);
        int n = gid >> 9;
        int k = gid & 511;
        float v = BETA * W1[k * 512 + n] + (k == n ? OMB : 0.0f);
        W1T[gid] = f2bf(v);
    }
    if (gid < NN) cnt[gid] = 0;
}

// ---------------- CSR build ----------------
__global__ void hist(const int* __restrict__ ei, int* __restrict__ cnt) {
    int e = blockIdx.x * 256 + threadIdx.x;
    if (e < NE) atomicAdd(&cnt[ei[NE + e]], 1);
}

#define SCAN_B 196   // ceil(50000/256)

__global__ __launch_bounds__(256) void scan1(const int* __restrict__ cnt, int* __restrict__ bsum) {
    __shared__ int red[4];
    int t = threadIdx.x;
    int i = blockIdx.x * 256 + t;
    int v = (i < NN) ? cnt[i] : 0;
#pragma unroll
    for (int off = 32; off; off >>= 1) v += __shfl_xor(v, off, 64);
    if ((t & 63) == 0) red[t >> 6] = v;
    __syncthreads();
    if (t == 0) bsum[blockIdx.x] = red[0] + red[1] + red[2] + red[3];
}

__global__ __launch_bounds__(256) void scan2(int* __restrict__ bsum, int* __restrict__ boff) {
    __shared__ int ls[256];
    int t = threadIdx.x;
    int v = (t < SCAN_B) ? bsum[t] : 0;
    ls[t] = v;
    __syncthreads();
    for (int off = 1; off < 256; off <<= 1) {
        int add = (t >= off) ? ls[t - off] : 0;
        __syncthreads();
        ls[t] += add;
        __syncthreads();
    }
    if (t < SCAN_B) boff[t] = ls[t] - v;   // exclusive
}

__global__ __launch_bounds__(256) void scan3(const int* __restrict__ cnt, const int* __restrict__ boff,
                                             int* __restrict__ rowptr, int* __restrict__ cursor) {
    __shared__ int ls[256];
    int t = threadIdx.x;
    int i = blockIdx.x * 256 + t;
    int v = (i < NN) ? cnt[i] : 0;
    ls[t] = v;
    __syncthreads();
    for (int off = 1; off < 256; off <<= 1) {
        int add = (t >= off) ? ls[t - off] : 0;
        __syncthreads();
        ls[t] += add;
        __syncthreads();
    }
    if (i < NN) {
        int pre = ls[t] - v + boff[blockIdx.x];
        rowptr[i] = pre;
        cursor[i] = pre;
    }
}

// (src, bits(0.9*w)) packed per slot: one 8B load per edge in gather
__global__ void fill_slots(const int* __restrict__ ei, const float* __restrict__ ew,
                           int* __restrict__ cursor, int2* __restrict__ eiw) {
    int e = blockIdx.x * 256 + threadIdx.x;
    if (e < NE) {
        int d = ei[NE + e];
        int p = atomicAdd(&cursor[d], 1);
        int2 sw;
        sw.x = ei[e];
        sw.y = __float_as_int(0.9f * ew[e]);
        eiw[p] = sw;
    }
}

// ---------------- fused gather + gemm ----------------
// block = 32 output rows, 512 threads (8 waves). Phase 1: each wave gathers 4
// node rows (agg = 0.1*x0 + sum w*xb[src]) into a swizzled bf16 LDS A-tile.
// Phase 2 (barrier-free k-loop): each wave owns 64 output cols; A from LDS,
// B fragments straight from global W1T (512 KB, L2/L1-resident).
__global__ __launch_bounds__(512, 4) void fused_gg(const u32x4e* __restrict__ xb,
                                                   const f32x4e* __restrict__ x0,
                                                   const int* __restrict__ rowptr,
                                                   const int* __restrict__ cnt,
                                                   const int2* __restrict__ eiw,
                                                   const unsigned short* __restrict__ W1T,
                                                   float* __restrict__ out) {
    __shared__ unsigned short Al[32 * 512];   // 32 KB, byte-swizzled rows
    int t = threadIdx.x;
    int lane = t & 63, w = t >> 6;
    int rowBase = blockIdx.x * 32;

    // ---- phase 1: gather ----
#define ACCUM(vv, ww)                                    \
    acc[0] += (ww) * u2f((vv).x << 16);                  \
    acc[1] += (ww) * u2f((vv).x & 0xffff0000u);          \
    acc[2] += (ww) * u2f((vv).y << 16);                  \
    acc[3] += (ww) * u2f((vv).y & 0xffff0000u);          \
    acc[4] += (ww) * u2f((vv).z << 16);                  \
    acc[5] += (ww) * u2f((vv).z & 0xffff0000u);          \
    acc[6] += (ww) * u2f((vv).w << 16);                  \
    acc[7] += (ww) * u2f((vv).w & 0xffff0000u);

    for (int q = 0; q < 4; ++q) {
        int row = w * 4 + q;
        int node = rowBase + row;
        float acc[8] = {0.f, 0.f, 0.f, 0.f, 0.f, 0.f, 0.f, 0.f};
        if (node < NN) {
            const f32x4e* x0r = x0 + (size_t)node * (CH / 4);
            f32x4e a0 = __builtin_nontemporal_load(&x0r[lane * 2]);
            f32x4e a1 = __builtin_nontemporal_load(&x0r[lane * 2 + 1]);
            acc[0] = 0.1f * a0.x; acc[1] = 0.1f * a0.y; acc[2] = 0.1f * a0.z; acc[3] = 0.1f * a0.w;
            acc[4] = 0.1f * a1.x; acc[5] = 0.1f * a1.y; acc[6] = 0.1f * a1.z; acc[7] = 0.1f * a1.w;

            int i   = __builtin_amdgcn_readfirstlane(rowptr[node]);
            int end = i + __builtin_amdgcn_readfirstlane(cnt[node]);
            for (; i + 8 <= end; i += 8) {
                int2 e[8];
#pragma unroll
                for (int j = 0; j < 8; ++j) e[j] = eiw[i + j];
                u32x4e v[8];
#pragma unroll
                for (int j = 0; j < 8; ++j) v[j] = xb[(size_t)e[j].x * (CH / 8) + lane];
#pragma unroll
                for (int j = 0; j < 8; ++j) { float ww = __int_as_float(e[j].y); ACCUM(v[j], ww) }
            }
            for (; i + 2 <= end; i += 2) {
                int2 e0 = eiw[i], e1 = eiw[i + 1];
                u32x4e v0 = xb[(size_t)e0.x * (CH / 8) + lane];
                u32x4e v1 = xb[(size_t)e1.x * (CH / 8) + lane];
                float w0 = __int_as_float(e0.y), w1 = __int_as_float(e1.y);
                ACCUM(v0, w0)
                ACCUM(v1, w1)
            }
            for (; i < end; ++i) {
                int2 e0 = eiw[i];
                u32x4e v0 = xb[(size_t)e0.x * (CH / 8) + lane];
                float w0 = __int_as_float(e0.y);
                ACCUM(v0, w0)
            }
        }
        uint4 o;
        o.x = (unsigned)f2bf(acc[0]) | ((unsigned)f2bf(acc[1]) << 16);
        o.y = (unsigned)f2bf(acc[2]) | ((unsigned)f2bf(acc[3]) << 16);
        o.z = (unsigned)f2bf(acc[4]) | ((unsigned)f2bf(acc[5]) << 16);
        o.w = (unsigned)f2bf(acc[6]) | ((unsigned)f2bf(acc[7]) << 16);
        *(uint4*)((char*)Al + row * 1024 + ((lane * 16) ^ ((row & 7) << 4))) = o;
    }
#undef ACCUM
    __syncthreads();

    // ---- phase 2: 32x512 = A(LDS) @ W1T(global), BK=32, no barriers ----
    f32x4 acc2[2][4] = {};
    int kg = lane >> 4;          // 0..3
    int kb = kg * 8;
    for (int k0 = 0; k0 < 512; k0 += 32) {
        bf16x8 af[2], bfr[4];
#pragma unroll
        for (int mi = 0; mi < 2; ++mi) {
            int row = mi * 16 + (lane & 15);
            af[mi] = *(const bf16x8*)((const char*)Al + row * 1024 +
                                      (((k0 + kb) * 2) ^ ((row & 7) << 4)));
        }
#pragma unroll
        for (int ni = 0; ni < 4; ++ni) {
            int col = w * 64 + ni * 16 + (lane & 15);
            bfr[ni] = *(const bf16x8*)(W1T + (size_t)col * 512 + k0 + kb);
        }
#pragma unroll
        for (int mi = 0; mi < 2; ++mi)
#pragma unroll
            for (int ni = 0; ni < 4; ++ni)
                acc2[mi][ni] = __builtin_amdgcn_mfma_f32_16x16x32_bf16(
                    af[mi], bfr[ni], acc2[mi][ni], 0, 0, 0);
    }

    // store: C/D mapping col=lane&15, row=(lane>>4)*4+j
#pragma unroll
    for (int mi = 0; mi < 2; ++mi) {
#pragma unroll
        for (int j = 0; j < 4; ++j) {
            int grow = rowBase + mi * 16 + kg * 4 + j;
            if (grow < NN) {
#pragma unroll
                for (int ni = 0; ni < 4; ++ni) {
                    __builtin_nontemporal_store(
                        acc2[mi][ni][j],
                        &out[(size_t)grow * 512 + w * 64 + ni * 16 + (lane & 15)]);
                }
            }
        }
    }
}

extern "C" void kernel_launch(void* const* d_in, const int* in_sizes, int n_in,
                              void* d_out, int out_size, void* d_ws, size_t ws_size,
                              hipStream_t stream) {
    const float* x  = (const float*)d_in[0];
    const float* x0 = (const float*)d_in[1];
    const float* W1 = (const float*)d_in[2];
    const float* ew = (const float*)d_in[3];
    const int*   ei = (const int*)d_in[4];
    float* out = (float*)d_out;

    char* ws = (char*)d_ws;
    u32x4e* xb           = (u32x4e*)(ws);                                // 51,200,000
    unsigned short* W1T  = (unsigned short*)(ws + 51249152);             // 524,288
    int*   cnt    = (int*)(ws + 51773440);                               // 200,000
    int*   rowptr = (int*)(ws + 51973440);                               // 200,000
    int*   cursor = (int*)(ws + 52173440);                               // 200,000
    int2*  eiw    = (int2*)(ws + 52373440);                              // 6,400,000
    int*   bsum   = (int*)(ws + 58773440);                               // 1,024
    int*   boff   = (int*)(ws + 58774464);                               // 1,024

    prologue<<<NN * CH / 8 / 256, 256, 0, stream>>>((const f32x4e*)x, xb, W1, W1T, cnt);
    hist<<<(NE + 255) / 256, 256, 0, stream>>>(ei, cnt);
    scan1<<<SCAN_B, 256, 0, stream>>>(cnt, bsum);
    scan2<<<1, 256, 0, stream>>>(bsum, boff);
    scan3<<<SCAN_B, 256, 0, stream>>>(cnt, boff, rowptr, cursor);
    fill_slots<<<(NE + 255) / 256, 256, 0, stream>>>(ei, ew, cursor, eiw);
    fused_gg<<<(NN + 31) / 32, 512, 0, stream>>>(xb, (const f32x4e*)x0, rowptr, cnt, eiw,
                                                 W1T, out);
}

// Round 9
// 332.257 us; speedup vs baseline: 1.0355x; 1.0355x over previous
//
#include <hip/hip_runtime.h>
#include <stdint.h>

#define NN 50000
#define NE 800000
#define CH 512

__device__ __forceinline__ unsigned short f2bf(float f) {
    union { float f; unsigned u; } v; v.f = f;
    unsigned u = v.u;
    unsigned r = u + 0x7FFFu + ((u >> 16) & 1u);
    return (unsigned short)(r >> 16);
}

__device__ __forceinline__ float u2f(unsigned u) {
    union { unsigned u; float f; } v; v.u = u;
    return v.f;
}

typedef short bf16x8 __attribute__((ext_vector_type(8)));
typedef float f32x4 __attribute__((ext_vector_type(4)));
typedef float f32x4e __attribute__((ext_vector_type(4)));
typedef unsigned u32x4e __attribute__((ext_vector_type(4)));

// ---------------- prologue: xb = bf16(x); W1T' transform; cnt = 0 ----------------
__global__ __launch_bounds__(256) void prologue(const f32x4e* __restrict__ x,
                                                u32x4e* __restrict__ xb,
                                                const float* __restrict__ W1,
                                                unsigned short* __restrict__ W1T,
                                                int* __restrict__ cnt) {
    int gid = blockIdx.x * 256 + threadIdx.x;   // 0 .. 3,199,999
    {
        f32x4e a = __builtin_nontemporal_load(&x[2 * gid]);
        f32x4e b = __builtin_nontemporal_load(&x[2 * gid + 1]);
        u32x4e o;
        o.x = (unsigned)f2bf(a.x) | ((unsigned)f2bf(a.y) << 16);
        o.y = (unsigned)f2bf(a.z) | ((unsigned)f2bf(a.w) << 16);
        o.z = (unsigned)f2bf(b.x) | ((unsigned)f2bf(b.y) << 16);
        o.w = (unsigned)f2bf(b.z) | ((unsigned)f2bf(b.w) << 16);
        xb[gid] = o;
    }
    if (gid < CH * CH) {
        const float BETA = 0.40546510810816438f;
        const float OMB  = (float)(1.0 - 0.40546510810816438);
        int n = gid >> 9;
        int k = gid & 511;
        float v = BETA * W1[k * 512 + n] + (k == n ? OMB : 0.0f);
        W1T[gid] = f2bf(v);
    }
    if (gid < NN) cnt[gid] = 0;
}

// ---------------- CSR build ----------------
__global__ void hist(const int* __restrict__ ei, int* __restrict__ cnt) {
    int e = blockIdx.x * 256 + threadIdx.x;
    if (e < NE) atomicAdd(&cnt[ei[NE + e]], 1);
}

#define SCAN_B 196   // ceil(50000/256)

__global__ __launch_bounds__(256) void scan1(const int* __restrict__ cnt, int* __restrict__ bsum) {
    __shared__ int red[4];
    int t = threadIdx.x;
    int i = blockIdx.x * 256 + t;
    int v = (i < NN) ? cnt[i] : 0;
#pragma unroll
    for (int off = 32; off; off >>= 1) v += __shfl_xor(v, off, 64);
    if ((t & 63) == 0) red[t >> 6] = v;
    __syncthreads();
    if (t == 0) bsum[blockIdx.x] = red[0] + red[1] + red[2] + red[3];
}

__global__ __launch_bounds__(256) void scan2(int* __restrict__ bsum, int* __restrict__ boff) {
    __shared__ int ls[256];
    int t = threadIdx.x;
    int v = (t < SCAN_B) ? bsum[t] : 0;
    ls[t] = v;
    __syncthreads();
    for (int off = 1; off < 256; off <<= 1) {
        int add = (t >= off) ? ls[t - off] : 0;
        __syncthreads();
        ls[t] += add;
        __syncthreads();
    }
    if (t < SCAN_B) boff[t] = ls[t] - v;   // exclusive
}

__global__ __launch_bounds__(256) void scan3(const int* __restrict__ cnt, const int* __restrict__ boff,
                                             int* __restrict__ rowptr, int* __restrict__ cursor) {
    __shared__ int ls[256];
    int t = threadIdx.x;
    int i = blockIdx.x * 256 + t;
    int v = (i < NN) ? cnt[i] : 0;
    ls[t] = v;
    __syncthreads();
    for (int off = 1; off < 256; off <<= 1) {
        int add = (t >= off) ? ls[t - off] : 0;
        __syncthreads();
        ls[t] += add;
        __syncthreads();
    }
    if (i < NN) {
        int pre = ls[t] - v + boff[blockIdx.x];
        rowptr[i] = pre;
        cursor[i] = pre;
    }
}

// (src, bits(0.9*w)) packed per slot: one 8B load per edge in gather
__global__ void fill_slots(const int* __restrict__ ei, const float* __restrict__ ew,
                           int* __restrict__ cursor, int2* __restrict__ eiw) {
    int e = blockIdx.x * 256 + threadIdx.x;
    if (e < NE) {
        int d = ei[NE + e];
        int p = atomicAdd(&cursor[d], 1);
        int2 sw;
        sw.x = ei[e];
        sw.y = __float_as_int(0.9f * ew[e]);
        eiw[p] = sw;
    }
}

// ---------------- gather: agg[node] = bf16(sum_e w*xb[src])  (NO x0 stream) ----------------
__global__ __launch_bounds__(256) void gather_nodes(const u32x4e* __restrict__ xb,
                                                    const int* __restrict__ rowptr,
                                                    const int* __restrict__ cnt,
                                                    const int2* __restrict__ eiw,
                                                    unsigned short* __restrict__ agg) {
    int node = blockIdx.x * 4 + (threadIdx.x >> 6);
    if (node >= NN) return;
    int lane = threadIdx.x & 63;

    float acc[8] = {0.f, 0.f, 0.f, 0.f, 0.f, 0.f, 0.f, 0.f};

    int i = rowptr[node];
    int end = i + cnt[node];

#define ACCUM(vv, ww)                                    \
    acc[0] += (ww) * u2f((vv).x << 16);                  \
    acc[1] += (ww) * u2f((vv).x & 0xffff0000u);          \
    acc[2] += (ww) * u2f((vv).y << 16);                  \
    acc[3] += (ww) * u2f((vv).y & 0xffff0000u);          \
    acc[4] += (ww) * u2f((vv).z << 16);                  \
    acc[5] += (ww) * u2f((vv).z & 0xffff0000u);          \
    acc[6] += (ww) * u2f((vv).w << 16);                  \
    acc[7] += (ww) * u2f((vv).w & 0xffff0000u);

    for (; i + 8 <= end; i += 8) {
        int2 e[8];
#pragma unroll
        for (int j = 0; j < 8; ++j) e[j] = eiw[i + j];
        u32x4e v[8];
#pragma unroll
        for (int j = 0; j < 8; ++j) v[j] = xb[(size_t)e[j].x * (CH / 8) + lane];
#pragma unroll
        for (int j = 0; j < 8; ++j) { float w = __int_as_float(e[j].y); ACCUM(v[j], w) }
    }
    for (; i + 2 <= end; i += 2) {
        int2 e0 = eiw[i], e1 = eiw[i + 1];
        u32x4e v0 = xb[(size_t)e0.x * (CH / 8) + lane];
        u32x4e v1 = xb[(size_t)e1.x * (CH / 8) + lane];
        float w0 = __int_as_float(e0.y), w1 = __int_as_float(e1.y);
        ACCUM(v0, w0)
        ACCUM(v1, w1)
    }
    for (; i < end; ++i) {
        int2 e0 = eiw[i];
        u32x4e v0 = xb[(size_t)e0.x * (CH / 8) + lane];
        float w0 = __int_as_float(e0.y);
        ACCUM(v0, w0)
    }
#undef ACCUM

    u32x4e o;
    o.x = (unsigned)f2bf(acc[0]) | ((unsigned)f2bf(acc[1]) << 16);
    o.y = (unsigned)f2bf(acc[2]) | ((unsigned)f2bf(acc[3]) << 16);
    o.z = (unsigned)f2bf(acc[4]) | ((unsigned)f2bf(acc[5]) << 16);
    o.w = (unsigned)f2bf(acc[6]) | ((unsigned)f2bf(acc[7]) << 16);
    *(u32x4e*)(agg + (size_t)node * CH + lane * 8) = o;
}

// ---------------- gemm512: out = (agg + 0.1*x0) @ W1'  ----------------
// BM=128, BN=512 (single col pass -> x0 read once), BK=32, 512 thr, 8 waves
// (2 row-halves x 4 col-quarters), acc[4][8]. LDS rows padded to 40 bf16
// (80 B) so stride-80 fragment reads are 2-way-per-bank (free).
__global__ __launch_bounds__(512) void gemm512(const unsigned short* __restrict__ agg,
                                               const float* __restrict__ x0,
                                               const unsigned short* __restrict__ W1T,
                                               float* __restrict__ out) {
    __shared__ unsigned short Al[128 * 40];   // 10,240 B
    __shared__ unsigned short Bl[512 * 40];   // 40,960 B
    int t = threadIdx.x;
    int lane = t & 63, w = t >> 6;
    int wm = w >> 2, wn = w & 3;
    int rowBase = blockIdx.x * 128;

    f32x4 acc[4][8] = {};

    for (int k0 = 0; k0 < 512; k0 += 32) {
        // stage A: 128 rows x 32 k; val = bf16(agg + 0.1*x0)
        {
            int arow = t >> 2;
            int k8 = (t & 3) * 8;
            int grow = rowBase + arow;
            if (grow > NN - 1) grow = NN - 1;   // clamp: stay in-bounds; tail rows unused
            size_t base = (size_t)grow * 512 + k0 + k8;
            uint4 ag = *(const uint4*)(agg + base);
            f32x4e xa = __builtin_nontemporal_load((const f32x4e*)(x0 + base));
            f32x4e xc = __builtin_nontemporal_load((const f32x4e*)(x0 + base + 4));
            float v0 = u2f(ag.x << 16)         + 0.1f * xa.x;
            float v1 = u2f(ag.x & 0xffff0000u) + 0.1f * xa.y;
            float v2 = u2f(ag.y << 16)         + 0.1f * xa.z;
            float v3 = u2f(ag.y & 0xffff0000u) + 0.1f * xa.w;
            float v4 = u2f(ag.z << 16)         + 0.1f * xc.x;
            float v5 = u2f(ag.z & 0xffff0000u) + 0.1f * xc.y;
            float v6 = u2f(ag.w << 16)         + 0.1f * xc.z;
            float v7 = u2f(ag.w & 0xffff0000u) + 0.1f * xc.w;
            uint4 o;
            o.x = (unsigned)f2bf(v0) | ((unsigned)f2bf(v1) << 16);
            o.y = (unsigned)f2bf(v2) | ((unsigned)f2bf(v3) << 16);
            o.z = (unsigned)f2bf(v4) | ((unsigned)f2bf(v5) << 16);
            o.w = (unsigned)f2bf(v6) | ((unsigned)f2bf(v7) << 16);
            *(uint4*)((char*)Al + arow * 80 + k8 * 2) = o;
        }
        // stage B: 512 cols x 32 k (W1T is L2-resident, 512 KB)
#pragma unroll
        for (int p = 0; p < 4; ++p) {
            int col = p * 128 + (t >> 2);
            int k8 = (t & 3) * 8;
            uint4 v = *(const uint4*)(W1T + (size_t)col * 512 + k0 + k8);
            *(uint4*)((char*)Bl + col * 80 + k8 * 2) = v;
        }
        __syncthreads();

        int kb = (lane >> 4) * 8;
        bf16x8 af[4], bfr[8];
#pragma unroll
        for (int mi = 0; mi < 4; ++mi) {
            int row = wm * 64 + mi * 16 + (lane & 15);
            af[mi] = *(const bf16x8*)((const char*)Al + row * 80 + kb * 2);
        }
#pragma unroll
        for (int ni = 0; ni < 8; ++ni) {
            int col = wn * 128 + ni * 16 + (lane & 15);
            bfr[ni] = *(const bf16x8*)((const char*)Bl + col * 80 + kb * 2);
        }
#pragma unroll
        for (int mi = 0; mi < 4; ++mi)
#pragma unroll
            for (int ni = 0; ni < 8; ++ni)
                acc[mi][ni] = __builtin_amdgcn_mfma_f32_16x16x32_bf16(
                    af[mi], bfr[ni], acc[mi][ni], 0, 0, 0);
        __syncthreads();
    }

    // store: C/D mapping col=lane&15, row=(lane>>4)*4+j
#pragma unroll
    for (int mi = 0; mi < 4; ++mi) {
#pragma unroll
        for (int j = 0; j < 4; ++j) {
            int grow = rowBase + wm * 64 + mi * 16 + (lane >> 4) * 4 + j;
            if (grow < NN) {
#pragma unroll
                for (int ni = 0; ni < 8; ++ni) {
                    __builtin_nontemporal_store(
                        acc[mi][ni][j],
                        &out[(size_t)grow * 512 + wn * 128 + ni * 16 + (lane & 15)]);
                }
            }
        }
    }
}

extern "C" void kernel_launch(void* const* d_in, const int* in_sizes, int n_in,
                              void* d_out, int out_size, void* d_ws, size_t ws_size,
                              hipStream_t stream) {
    const float* x  = (const float*)d_in[0];
    const float* x0 = (const float*)d_in[1];
    const float* W1 = (const float*)d_in[2];
    const float* ew = (const float*)d_in[3];
    const int*   ei = (const int*)d_in[4];
    float* out = (float*)d_out;

    char* ws = (char*)d_ws;
    unsigned short* agg  = (unsigned short*)(ws);                        // 50048*512*2 = 51,249,152
    unsigned short* W1T  = (unsigned short*)(ws + 51249152);             // 524,288
    int*   cnt    = (int*)(ws + 51773440);                               // 200,000
    int*   rowptr = (int*)(ws + 51973440);                               // 200,000
    int*   cursor = (int*)(ws + 52173440);                               // 200,000
    int2*  eiw    = (int2*)(ws + 52373440);                              // 6,400,000
    int*   bsum   = (int*)(ws + 58773440);                               // 1,024
    int*   boff   = (int*)(ws + 58774464);                               // 1,024

    // xb (bf16 copy of x, 51.2 MB) lives in d_out scratch: read only by
    // gather_nodes; gemm512 fully overwrites d_out afterwards.
    u32x4e* xb = (u32x4e*)d_out;

    prologue<<<NN * CH / 8 / 256, 256, 0, stream>>>((const f32x4e*)x, xb, W1, W1T, cnt);
    hist<<<(NE + 255) / 256, 256, 0, stream>>>(ei, cnt);
    scan1<<<SCAN_B, 256, 0, stream>>>(cnt, bsum);
    scan2<<<1, 256, 0, stream>>>(bsum, boff);
    scan3<<<SCAN_B, 256, 0, stream>>>(cnt, boff, rowptr, cursor);
    fill_slots<<<(NE + 255) / 256, 256, 0, stream>>>(ei, ew, cursor, eiw);
    gather_nodes<<<(NN + 3) / 4, 256, 0, stream>>>(xb, rowptr, cnt, eiw, agg);
    gemm512<<<(NN + 127) / 128, 512, 0, stream>>>(agg, x0, W1T, out);
}

// Round 16
// 301.407 us; speedup vs baseline: 1.1415x; 1.1024x over previous
//
#include <hip/hip_runtime.h>
#include <stdint.h>

#define NN 50000
#define NE 800000
#define CH 512

__device__ __forceinline__ unsigned short f2bf(float f) {
    union { float f; unsigned u; } v; v.f = f;
    unsigned u = v.u;
    unsigned r = u + 0x7FFFu + ((u >> 16) & 1u);
    return (unsigned short)(r >> 16);
}

__device__ __forceinline__ float u2f(unsigned u) {
    union { unsigned u; float f; } v; v.u = u;
    return v.f;
}

typedef short bf16x8 __attribute__((ext_vector_type(8)));
typedef float f32x4 __attribute__((ext_vector_type(4)));

// ---------------- prologue: xb = bf16(x); W1T' transform; cnt = 0 ----------------
__global__ __launch_bounds__(256) void prologue(const float4* __restrict__ x,
                                                uint4* __restrict__ xb,
                                                const float* __restrict__ W1,
                                                unsigned short* __restrict__ W1T,
                                                int* __restrict__ cnt) {
    int gid = blockIdx.x * 256 + threadIdx.x;   // 0 .. 3,199,999
    {
        float4 a = x[2 * gid];
        float4 b = x[2 * gid + 1];
        uint4 o;
        o.x = (unsigned)f2bf(a.x) | ((unsigned)f2bf(a.y) << 16);
        o.y = (unsigned)f2bf(a.z) | ((unsigned)f2bf(a.w) << 16);
        o.z = (unsigned)f2bf(b.x) | ((unsigned)f2bf(b.y) << 16);
        o.w = (unsigned)f2bf(b.z) | ((unsigned)f2bf(b.w) << 16);
        xb[gid] = o;
    }
    if (gid < CH * CH) {
        const float BETA = 0.40546510810816438f;
        const float OMB  = (float)(1.0 - 0.40546510810816438);
        int n = gid >> 9;
        int k = gid & 511;
        float v = BETA * W1[k * 512 + n] + (k == n ? OMB : 0.0f);
        W1T[gid] = f2bf(v);
    }
    if (gid < NN) cnt[gid] = 0;
}

// ---------------- CSR build ----------------
__global__ void hist(const int* __restrict__ ei, int* __restrict__ cnt) {
    int e = blockIdx.x * 256 + threadIdx.x;
    if (e < NE) atomicAdd(&cnt[ei[NE + e]], 1);
}

#define SCAN_B 196   // ceil(50000/256)

__global__ __launch_bounds__(256) void scan1(const int* __restrict__ cnt, int* __restrict__ bsum) {
    __shared__ int red[4];
    int t = threadIdx.x;
    int i = blockIdx.x * 256 + t;
    int v = (i < NN) ? cnt[i] : 0;
#pragma unroll
    for (int off = 32; off; off >>= 1) v += __shfl_xor(v, off, 64);
    if ((t & 63) == 0) red[t >> 6] = v;
    __syncthreads();
    if (t == 0) bsum[blockIdx.x] = red[0] + red[1] + red[2] + red[3];
}

__global__ __launch_bounds__(256) void scan2(int* __restrict__ bsum, int* __restrict__ boff) {
    __shared__ int ls[256];
    int t = threadIdx.x;
    int v = (t < SCAN_B) ? bsum[t] : 0;
    ls[t] = v;
    __syncthreads();
    for (int off = 1; off < 256; off <<= 1) {
        int add = (t >= off) ? ls[t - off] : 0;
        __syncthreads();
        ls[t] += add;
        __syncthreads();
    }
    if (t < SCAN_B) boff[t] = ls[t] - v;   // exclusive
}

__global__ __launch_bounds__(256) void scan3(const int* __restrict__ cnt, const int* __restrict__ boff,
                                             int* __restrict__ rowptr, int* __restrict__ cursor) {
    __shared__ int ls[256];
    int t = threadIdx.x;
    int i = blockIdx.x * 256 + t;
    int v = (i < NN) ? cnt[i] : 0;
    ls[t] = v;
    __syncthreads();
    for (int off = 1; off < 256; off <<= 1) {
        int add = (t >= off) ? ls[t - off] : 0;
        __syncthreads();
        ls[t] += add;
        __syncthreads();
    }
    if (i < NN) {
        int pre = ls[t] - v + boff[blockIdx.x];
        rowptr[i] = pre;
        cursor[i] = pre;
    }
}

// (src, bits(0.9*w)) packed per slot: one 8B load per edge in gather.
// The bounds guard is a no-op for correct cursor state (sum cnt == NE);
// insurance against wild scatter if upstream state were ever corrupted.
__global__ void fill_slots(const int* __restrict__ ei, const float* __restrict__ ew,
                           int* __restrict__ cursor, int2* __restrict__ eiw) {
    int e = blockIdx.x * 256 + threadIdx.x;
    if (e < NE) {
        int d = ei[NE + e];
        int p = atomicAdd(&cursor[d], 1);
        int2 sw;
        sw.x = ei[e];
        sw.y = __float_as_int(0.9f * ew[e]);
        if ((unsigned)p < (unsigned)NE) eiw[p] = sw;
    }
}

// ---------------- gather: hb[node] = bf16(0.1*x0[node] + sum_e w*xb[src]) ----------------
// batched x8 for memory-level parallelism: 8 independent 1KB row loads in flight
__global__ __launch_bounds__(256) void gather_nodes(const uint4* __restrict__ xb,
                                                    const float4* __restrict__ x0,
                                                    const int* __restrict__ rowptr,
                                                    const int* __restrict__ cnt,
                                                    const int2* __restrict__ eiw,
                                                    unsigned short* __restrict__ hb) {
    int node = blockIdx.x * 4 + (threadIdx.x >> 6);
    if (node >= NN) return;
    int lane = threadIdx.x & 63;

    const float4* x0r = x0 + (size_t)node * (CH / 4);
    float4 a0 = x0r[lane * 2];
    float4 a1 = x0r[lane * 2 + 1];
    float acc[8];
    acc[0] = 0.1f * a0.x; acc[1] = 0.1f * a0.y; acc[2] = 0.1f * a0.z; acc[3] = 0.1f * a0.w;
    acc[4] = 0.1f * a1.x; acc[5] = 0.1f * a1.y; acc[6] = 0.1f * a1.z; acc[7] = 0.1f * a1.w;

    int i = rowptr[node];
    int end = i + cnt[node];

#define ACCUM(vv, ww)                                    \
    acc[0] += (ww) * u2f((vv).x << 16);                  \
    acc[1] += (ww) * u2f((vv).x & 0xffff0000u);          \
    acc[2] += (ww) * u2f((vv).y << 16);                  \
    acc[3] += (ww) * u2f((vv).y & 0xffff0000u);          \
    acc[4] += (ww) * u2f((vv).z << 16);                  \
    acc[5] += (ww) * u2f((vv).z & 0xffff0000u);          \
    acc[6] += (ww) * u2f((vv).w << 16);                  \
    acc[7] += (ww) * u2f((vv).w & 0xffff0000u);

    for (; i + 8 <= end; i += 8) {
        int2 e[8];
#pragma unroll
        for (int j = 0; j < 8; ++j) e[j] = eiw[i + j];
        uint4 v[8];
#pragma unroll
        for (int j = 0; j < 8; ++j) v[j] = xb[(size_t)e[j].x * (CH / 8) + lane];
#pragma unroll
        for (int j = 0; j < 8; ++j) { float w = __int_as_float(e[j].y); ACCUM(v[j], w) }
    }
    for (; i + 2 <= end; i += 2) {
        int2 e0 = eiw[i], e1 = eiw[i + 1];
        uint4 v0 = xb[(size_t)e0.x * (CH / 8) + lane];
        uint4 v1 = xb[(size_t)e1.x * (CH / 8) + lane];
        float w0 = __int_as_float(e0.y), w1 = __int_as_float(e1.y);
        ACCUM(v0, w0)
        ACCUM(v1, w1)
    }
    for (; i < end; ++i) {
        int2 e0 = eiw[i];
        uint4 v0 = xb[(size_t)e0.x * (CH / 8) + lane];
        float w0 = __int_as_float(e0.y);
        ACCUM(v0, w0)
    }
#undef ACCUM

    uint4 o;
    o.x = (unsigned)f2bf(acc[0]) | ((unsigned)f2bf(acc[1]) << 16);
    o.y = (unsigned)f2bf(acc[2]) | ((unsigned)f2bf(acc[3]) << 16);
    o.z = (unsigned)f2bf(acc[4]) | ((unsigned)f2bf(acc[5]) << 16);
    o.w = (unsigned)f2bf(acc[6]) | ((unsigned)f2bf(acc[7]) << 16);
    *(uint4*)(hb + (size_t)node * CH + lane * 8) = o;
}

// ---------------- gemm: out = hb @ W1'  (bf16 MFMA, f32 acc) ----------------
// tile 128x256, 8 waves (2x4), LDS A 16KB + B 32KB, XOR-swizzled
__global__ __launch_bounds__(512) void gemm_out(const unsigned short* __restrict__ hb,
                                                const unsigned short* __restrict__ W1T,
                                                float* __restrict__ out) {
    __shared__ unsigned short Al[128 * 64];
    __shared__ unsigned short Bl[256 * 64];
    int t = threadIdx.x;
    int lane = t & 63, w = t >> 6;
    int wm = w & 1, wn = w >> 1;
    int rowBase = blockIdx.y * 128;
    int colBase = blockIdx.x * 256;

    f32x4 acc[4][4] = {};

    for (int k0 = 0; k0 < 512; k0 += 64) {
#pragma unroll
        for (int p = 0; p < 2; ++p) {
            int row = p * 64 + (t >> 3);
            int k8 = (t & 7) * 8;
            uint4 v = *(const uint4*)(hb + (size_t)(rowBase + row) * 512 + k0 + k8);
            int addr = (row * 128 + k8 * 2) ^ ((row & 7) << 4);
            *(uint4*)((char*)Al + addr) = v;
        }
#pragma unroll
        for (int p = 0; p < 4; ++p) {
            int col = p * 64 + (t >> 3);
            int k8 = (t & 7) * 8;
            uint4 v = *(const uint4*)(W1T + (size_t)(colBase + col) * 512 + k0 + k8);
            int addr = (col * 128 + k8 * 2) ^ ((col & 7) << 4);
            *(uint4*)((char*)Bl + addr) = v;
        }
        __syncthreads();

#pragma unroll
        for (int kk = 0; kk < 2; ++kk) {
            bf16x8 af[4], bfr[4];
            int kb = kk * 32 + (lane >> 4) * 8;
#pragma unroll
            for (int mi = 0; mi < 4; ++mi) {
                int row = wm * 64 + mi * 16 + (lane & 15);
                int addr = (row * 128 + kb * 2) ^ ((row & 7) << 4);
                af[mi] = *(const bf16x8*)((const char*)Al + addr);
            }
#pragma unroll
            for (int ni = 0; ni < 4; ++ni) {
                int col = wn * 64 + ni * 16 + (lane & 15);
                int addr = (col * 128 + kb * 2) ^ ((col & 7) << 4);
                bfr[ni] = *(const bf16x8*)((const char*)Bl + addr);
            }
#pragma unroll
            for (int mi = 0; mi < 4; ++mi)
#pragma unroll
                for (int ni = 0; ni < 4; ++ni)
                    acc[mi][ni] = __builtin_amdgcn_mfma_f32_16x16x32_bf16(
                        af[mi], bfr[ni], acc[mi][ni], 0, 0, 0);
        }
        __syncthreads();
    }

#pragma unroll
    for (int mi = 0; mi < 4; ++mi) {
#pragma unroll
        for (int j = 0; j < 4; ++j) {
            int grow = rowBase + wm * 64 + mi * 16 + (lane >> 4) * 4 + j;
            if (grow < NN) {
#pragma unroll
                for (int ni = 0; ni < 4; ++ni) {
                    out[(size_t)grow * 512 + colBase + wn * 64 + ni * 16 + (lane & 15)] =
                        acc[mi][ni][j];
                }
            }
        }
    }
}

extern "C" void kernel_launch(void* const* d_in, const int* in_sizes, int n_in,
                              void* d_out, int out_size, void* d_ws, size_t ws_size,
                              hipStream_t stream) {
    const float* x  = (const float*)d_in[0];
    const float* x0 = (const float*)d_in[1];
    const float* W1 = (const float*)d_in[2];
    const float* ew = (const float*)d_in[3];
    const int*   ei = (const int*)d_in[4];
    float* out = (float*)d_out;

    char* ws = (char*)d_ws;
    unsigned short* hb   = (unsigned short*)(ws);                        // 50048*512*2 = 51,249,152
    unsigned short* W1T  = (unsigned short*)(ws + 51249152);             // 524,288
    int*   cnt    = (int*)(ws + 51773440);                               // 200,000
    int*   rowptr = (int*)(ws + 51973440);                               // 200,000
    int*   cursor = (int*)(ws + 52173440);                               // 200,000
    int2*  eiw    = (int2*)(ws + 52373440);                              // 6,400,000
    int*   bsum   = (int*)(ws + 58773440);                               // 1,024
    int*   boff   = (int*)(ws + 58774464);                               // 1,024

    // xb (bf16 copy of x, 51.2 MB) lives in d_out scratch: read only by
    // gather_nodes; gemm_out fully overwrites d_out afterwards.
    uint4* xb = (uint4*)d_out;

    prologue<<<NN * CH / 8 / 256, 256, 0, stream>>>((const float4*)x, xb, W1, W1T, cnt);
    hist<<<(NE + 255) / 256, 256, 0, stream>>>(ei, cnt);
    scan1<<<SCAN_B, 256, 0, stream>>>(cnt, bsum);
    scan2<<<1, 256, 0, stream>>>(bsum, boff);
    scan3<<<SCAN_B, 256, 0, stream>>>(cnt, boff, rowptr, cursor);
    fill_slots<<<(NE + 255) / 256, 256, 0, stream>>>(ei, ew, cursor, eiw);
    gather_nodes<<<(NN + 3) / 4, 256, 0, stream>>>(xb, (const float4*)x0, rowptr, cnt, eiw, hb);
    gemm_out<<<dim3(2, 391), 512, 0, stream>>>(hb, W1T, out);
}

// Round 17
// 297.475 us; speedup vs baseline: 1.1566x; 1.0132x over previous
//
#include <hip/hip_runtime.h>
#include <stdint.h>

#define NN 50000
#define NE 800000
#define CH 512

__device__ __forceinline__ unsigned short f2bf(float f) {
    union { float f; unsigned u; } v; v.f = f;
    unsigned u = v.u;
    unsigned r = u + 0x7FFFu + ((u >> 16) & 1u);
    return (unsigned short)(r >> 16);
}

__device__ __forceinline__ float u2f(unsigned u) {
    union { unsigned u; float f; } v; v.u = u;
    return v.f;
}

typedef short bf16x8 __attribute__((ext_vector_type(8)));
typedef float f32x4 __attribute__((ext_vector_type(4)));

// ---------------- zero_cnt: cnt = 0 (must precede prologue's atomics) ----------------
__global__ void zero_cnt(int* __restrict__ cnt) {
    int i = blockIdx.x * 256 + threadIdx.x;
    if (i < NN) cnt[i] = 0;
}

// ---------------- prologue: xb = bf16(x); W1T' transform; hist ----------------
__global__ __launch_bounds__(256) void prologue(const float4* __restrict__ x,
                                                uint4* __restrict__ xb,
                                                const float* __restrict__ W1,
                                                unsigned short* __restrict__ W1T,
                                                const int* __restrict__ ei,
                                                int* __restrict__ cnt) {
    int gid = blockIdx.x * 256 + threadIdx.x;   // 0 .. 3,199,999
    {
        float4 a = x[2 * gid];
        float4 b = x[2 * gid + 1];
        uint4 o;
        o.x = (unsigned)f2bf(a.x) | ((unsigned)f2bf(a.y) << 16);
        o.y = (unsigned)f2bf(a.z) | ((unsigned)f2bf(a.w) << 16);
        o.z = (unsigned)f2bf(b.x) | ((unsigned)f2bf(b.y) << 16);
        o.w = (unsigned)f2bf(b.z) | ((unsigned)f2bf(b.w) << 16);
        xb[gid] = o;
    }
    if (gid < CH * CH) {
        const float BETA = 0.40546510810816438f;
        const float OMB  = (float)(1.0 - 0.40546510810816438);
        int n = gid >> 9;
        int k = gid & 511;
        float v = BETA * W1[k * 512 + n] + (k == n ? OMB : 0.0f);
        W1T[gid] = f2bf(v);
    }
    // hist folded in: cnt pre-zeroed by zero_cnt (stream-ordered before us)
    if (gid < NE) atomicAdd(&cnt[ei[NE + gid]], 1);
}

#define SCAN_B 196   // ceil(50000/256)

__global__ __launch_bounds__(256) void scan1(const int* __restrict__ cnt, int* __restrict__ bsum) {
    __shared__ int red[4];
    int t = threadIdx.x;
    int i = blockIdx.x * 256 + t;
    int v = (i < NN) ? cnt[i] : 0;
#pragma unroll
    for (int off = 32; off; off >>= 1) v += __shfl_xor(v, off, 64);
    if ((t & 63) == 0) red[t >> 6] = v;
    __syncthreads();
    if (t == 0) bsum[blockIdx.x] = red[0] + red[1] + red[2] + red[3];
}

// merged scan2+scan3: every block re-scans the 196 block sums in LDS (~1 us
// redundant work), then local-scans its own 256 counts. One fewer launch.
__global__ __launch_bounds__(256) void scan23(const int* __restrict__ cnt,
                                              const int* __restrict__ bsum,
                                              int* __restrict__ rowptr,
                                              int* __restrict__ cursor) {
    __shared__ int bs[256];
    __shared__ int ls[256];
    int t = threadIdx.x;
    int bid = blockIdx.x;
    bs[t] = (t < SCAN_B) ? bsum[t] : 0;
    __syncthreads();
    for (int off = 1; off < 256; off <<= 1) {
        int add = (t >= off) ? bs[t - off] : 0;
        __syncthreads();
        bs[t] += add;
        __syncthreads();
    }
    int boffv = (bid == 0) ? 0 : bs[bid - 1];   // exclusive block offset
    int i = bid * 256 + t;
    int v = (i < NN) ? cnt[i] : 0;
    ls[t] = v;
    __syncthreads();
    for (int off = 1; off < 256; off <<= 1) {
        int add = (t >= off) ? ls[t - off] : 0;
        __syncthreads();
        ls[t] += add;
        __syncthreads();
    }
    if (i < NN) {
        int pre = ls[t] - v + boffv;
        rowptr[i] = pre;
        cursor[i] = pre;
    }
}

// (src, bits(0.9*w)) packed per slot: one 8B load per edge in gather.
// The bounds guard is a no-op for correct cursor state (sum cnt == NE);
// insurance against wild scatter if upstream state were ever corrupted.
__global__ void fill_slots(const int* __restrict__ ei, const float* __restrict__ ew,
                           int* __restrict__ cursor, int2* __restrict__ eiw) {
    int e = blockIdx.x * 256 + threadIdx.x;
    if (e < NE) {
        int d = ei[NE + e];
        int p = atomicAdd(&cursor[d], 1);
        int2 sw;
        sw.x = ei[e];
        sw.y = __float_as_int(0.9f * ew[e]);
        if ((unsigned)p < (unsigned)NE) eiw[p] = sw;
    }
}

// ---------------- gather: hb[node] = bf16(0.1*x0[node] + sum_e w*xb[src]) ----------------
// batched x8 for memory-level parallelism: 8 independent 1KB row loads in flight
__global__ __launch_bounds__(256) void gather_nodes(const uint4* __restrict__ xb,
                                                    const float4* __restrict__ x0,
                                                    const int* __restrict__ rowptr,
                                                    const int* __restrict__ cnt,
                                                    const int2* __restrict__ eiw,
                                                    unsigned short* __restrict__ hb) {
    int node = blockIdx.x * 4 + (threadIdx.x >> 6);
    if (node >= NN) return;
    int lane = threadIdx.x & 63;

    const float4* x0r = x0 + (size_t)node * (CH / 4);
    float4 a0 = x0r[lane * 2];
    float4 a1 = x0r[lane * 2 + 1];
    float acc[8];
    acc[0] = 0.1f * a0.x; acc[1] = 0.1f * a0.y; acc[2] = 0.1f * a0.z; acc[3] = 0.1f * a0.w;
    acc[4] = 0.1f * a1.x; acc[5] = 0.1f * a1.y; acc[6] = 0.1f * a1.z; acc[7] = 0.1f * a1.w;

    int i = rowptr[node];
    int end = i + cnt[node];

#define ACCUM(vv, ww)                                    \
    acc[0] += (ww) * u2f((vv).x << 16);                  \
    acc[1] += (ww) * u2f((vv).x & 0xffff0000u);          \
    acc[2] += (ww) * u2f((vv).y << 16);                  \
    acc[3] += (ww) * u2f((vv).y & 0xffff0000u);          \
    acc[4] += (ww) * u2f((vv).z << 16);                  \
    acc[5] += (ww) * u2f((vv).z & 0xffff0000u);          \
    acc[6] += (ww) * u2f((vv).w << 16);                  \
    acc[7] += (ww) * u2f((vv).w & 0xffff0000u);

    for (; i + 8 <= end; i += 8) {
        int2 e[8];
#pragma unroll
        for (int j = 0; j < 8; ++j) e[j] = eiw[i + j];
        uint4 v[8];
#pragma unroll
        for (int j = 0; j < 8; ++j) v[j] = xb[(size_t)e[j].x * (CH / 8) + lane];
#pragma unroll
        for (int j = 0; j < 8; ++j) { float w = __int_as_float(e[j].y); ACCUM(v[j], w) }
    }
    for (; i + 2 <= end; i += 2) {
        int2 e0 = eiw[i], e1 = eiw[i + 1];
        uint4 v0 = xb[(size_t)e0.x * (CH / 8) + lane];
        uint4 v1 = xb[(size_t)e1.x * (CH / 8) + lane];
        float w0 = __int_as_float(e0.y), w1 = __int_as_float(e1.y);
        ACCUM(v0, w0)
        ACCUM(v1, w1)
    }
    for (; i < end; ++i) {
        int2 e0 = eiw[i];
        uint4 v0 = xb[(size_t)e0.x * (CH / 8) + lane];
        float w0 = __int_as_float(e0.y);
        ACCUM(v0, w0)
    }
#undef ACCUM

    uint4 o;
    o.x = (unsigned)f2bf(acc[0]) | ((unsigned)f2bf(acc[1]) << 16);
    o.y = (unsigned)f2bf(acc[2]) | ((unsigned)f2bf(acc[3]) << 16);
    o.z = (unsigned)f2bf(acc[4]) | ((unsigned)f2bf(acc[5]) << 16);
    o.w = (unsigned)f2bf(acc[6]) | ((unsigned)f2bf(acc[7]) << 16);
    *(uint4*)(hb + (size_t)node * CH + lane * 8) = o;
}

// ---------------- gemm: out = hb @ W1'  (bf16 MFMA, f32 acc) ----------------
// tile 128x256, 8 waves (2x4), LDS A 16KB + B 32KB, XOR-swizzled
__global__ __launch_bounds__(512) void gemm_out(const unsigned short* __restrict__ hb,
                                                const unsigned short* __restrict__ W1T,
                                                float* __restrict__ out) {
    __shared__ unsigned short Al[128 * 64];
    __shared__ unsigned short Bl[256 * 64];
    int t = threadIdx.x;
    int lane = t & 63, w = t >> 6;
    int wm = w & 1, wn = w >> 1;
    int rowBase = blockIdx.y * 128;
    int colBase = blockIdx.x * 256;

    f32x4 acc[4][4] = {};

    for (int k0 = 0; k0 < 512; k0 += 64) {
#pragma unroll
        for (int p = 0; p < 2; ++p) {
            int row = p * 64 + (t >> 3);
            int k8 = (t & 7) * 8;
            uint4 v = *(const uint4*)(hb + (size_t)(rowBase + row) * 512 + k0 + k8);
            int addr = (row * 128 + k8 * 2) ^ ((row & 7) << 4);
            *(uint4*)((char*)Al + addr) = v;
        }
#pragma unroll
        for (int p = 0; p < 4; ++p) {
            int col = p * 64 + (t >> 3);
            int k8 = (t & 7) * 8;
            uint4 v = *(const uint4*)(W1T + (size_t)(colBase + col) * 512 + k0 + k8);
            int addr = (col * 128 + k8 * 2) ^ ((col & 7) << 4);
            *(uint4*)((char*)Bl + addr) = v;
        }
        __syncthreads();

#pragma unroll
        for (int kk = 0; kk < 2; ++kk) {
            bf16x8 af[4], bfr[4];
            int kb = kk * 32 + (lane >> 4) * 8;
#pragma unroll
            for (int mi = 0; mi < 4; ++mi) {
                int row = wm * 64 + mi * 16 + (lane & 15);
                int addr = (row * 128 + kb * 2) ^ ((row & 7) << 4);
                af[mi] = *(const bf16x8*)((const char*)Al + addr);
            }
#pragma unroll
            for (int ni = 0; ni < 4; ++ni) {
                int col = wn * 64 + ni * 16 + (lane & 15);
                int addr = (col * 128 + kb * 2) ^ ((col & 7) << 4);
                bfr[ni] = *(const bf16x8*)((const char*)Bl + addr);
            }
#pragma unroll
            for (int mi = 0; mi < 4; ++mi)
#pragma unroll
                for (int ni = 0; ni < 4; ++ni)
                    acc[mi][ni] = __builtin_amdgcn_mfma_f32_16x16x32_bf16(
                        af[mi], bfr[ni], acc[mi][ni], 0, 0, 0);
        }
        __syncthreads();
    }

#pragma unroll
    for (int mi = 0; mi < 4; ++mi) {
#pragma unroll
        for (int j = 0; j < 4; ++j) {
            int grow = rowBase + wm * 64 + mi * 16 + (lane >> 4) * 4 + j;
            if (grow < NN) {
#pragma unroll
                for (int ni = 0; ni < 4; ++ni) {
                    out[(size_t)grow * 512 + colBase + wn * 64 + ni * 16 + (lane & 15)] =
                        acc[mi][ni][j];
                }
            }
        }
    }
}

extern "C" void kernel_launch(void* const* d_in, const int* in_sizes, int n_in,
                              void* d_out, int out_size, void* d_ws, size_t ws_size,
                              hipStream_t stream) {
    const float* x  = (const float*)d_in[0];
    const float* x0 = (const float*)d_in[1];
    const float* W1 = (const float*)d_in[2];
    const float* ew = (const float*)d_in[3];
    const int*   ei = (const int*)d_in[4];
    float* out = (float*)d_out;

    char* ws = (char*)d_ws;
    unsigned short* hb   = (unsigned short*)(ws);                        // 50048*512*2 = 51,249,152
    unsigned short* W1T  = (unsigned short*)(ws + 51249152);             // 524,288
    int*   cnt    = (int*)(ws + 51773440);                               // 200,000
    int*   rowptr = (int*)(ws + 51973440);                               // 200,000
    int*   cursor = (int*)(ws + 52173440);                               // 200,000
    int2*  eiw    = (int2*)(ws + 52373440);                              // 6,400,000
    int*   bsum   = (int*)(ws + 58773440);                               // 1,024

    // xb (bf16 copy of x, 51.2 MB) lives in d_out scratch: read only by
    // gather_nodes; gemm_out fully overwrites d_out afterwards.
    uint4* xb = (uint4*)d_out;

    zero_cnt<<<(NN + 255) / 256, 256, 0, stream>>>(cnt);
    prologue<<<NN * CH / 8 / 256, 256, 0, stream>>>((const float4*)x, xb, W1, W1T, ei, cnt);
    scan1<<<SCAN_B, 256, 0, stream>>>(cnt, bsum);
    scan23<<<SCAN_B, 256, 0, stream>>>(cnt, bsum, rowptr, cursor);
    fill_slots<<<(NE + 255) / 256, 256, 0, stream>>>(ei, ew, cursor, eiw);
    gather_nodes<<<(NN + 3) / 4, 256, 0, stream>>>(xb, (const float4*)x0, rowptr, cnt, eiw, hb);
    gemm_out<<<dim3(2, 391), 512, 0, stream>>>(hb, W1T, out);
}